// Round 6
// baseline (497.059 us; speedup 1.0000x reference)
//
#include <hip/hip_runtime.h>

typedef __attribute__((ext_vector_type(4))) float f32x4;
typedef __attribute__((ext_vector_type(8))) short short8;
typedef __attribute__((ext_vector_type(4))) unsigned short u16x4;

#define AS1 __attribute__((address_space(1)))
#define AS3 __attribute__((address_space(3)))

__device__ __forceinline__ unsigned short f2bf(float f) {
  unsigned u = __float_as_uint(f);
  return (unsigned short)((u + 0x7FFFu + ((u >> 16) & 1u)) >> 16);
}
__device__ __forceinline__ unsigned short f2bf_fast(float f) {
  return (unsigned short)((__float_as_uint(f) + 0x8000u) >> 16);
}

// ---------- LayerNorm fp32 -> bf16 into zero-padded (B, 3+N+3, D) ----------
__global__ __launch_bounds__(256) void ln_kernel(
    const float* __restrict__ x, const float* __restrict__ lw,
    const float* __restrict__ lb, unsigned short* __restrict__ xpad) {
  __shared__ float red[8];
  int row = blockIdx.x;                  // 0..8191
  int b = row >> 12, n = row & 4095;
  const float* xr = x + (size_t)row * 1024;
  int c = threadIdx.x * 4;
  f32x4 v = *(const f32x4*)(xr + c);
  float s = v[0] + v[1] + v[2] + v[3];
  float sq = v[0]*v[0] + v[1]*v[1] + v[2]*v[2] + v[3]*v[3];
#pragma unroll
  for (int off = 32; off; off >>= 1) {
    s  += __shfl_xor(s, off, 64);
    sq += __shfl_xor(sq, off, 64);
  }
  int w = threadIdx.x >> 6;
  if ((threadIdx.x & 63) == 0) { red[w*2] = s; red[w*2+1] = sq; }
  __syncthreads();
  float S  = red[0]+red[2]+red[4]+red[6];
  float SQ = red[1]+red[3]+red[5]+red[7];
  float mean = S * (1.0f/1024.0f);
  float var  = SQ * (1.0f/1024.0f) - mean*mean;
  float rstd = rsqrtf(var + 1e-5f);
  f32x4 wv = *(const f32x4*)(lw + c);
  f32x4 bv = *(const f32x4*)(lb + c);
  u16x4 o;
#pragma unroll
  for (int r = 0; r < 4; ++r) o[r] = f2bf((v[r]-mean)*rstd*wv[r] + bv[r]);
  *(u16x4*)(xpad + (((size_t)(b*4102 + n + 3)) << 10) + c) = o;
}

// ---------- Repack W (O,I,K) fp32 -> Wt rows (kk=k*1024+i) bf16 ----------
__global__ __launch_bounds__(256) void repack_kernel(
    const float* __restrict__ Wk, const float* __restrict__ Wv,
    const float* __restrict__ Wq, unsigned short* __restrict__ Wt) {
  __shared__ unsigned short t[7168];
  const float* W = (blockIdx.y == 0) ? Wk : (blockIdx.y == 1) ? Wv : Wq;
  int o = blockIdx.x;
  const float* row = W + (size_t)o * 7168;
  unsigned short* orow = Wt + ((size_t)(blockIdx.y * 1024 + o)) * 7168;
#pragma unroll
  for (int p = 0; p < 7; ++p) {
    int idx = p*1024 + threadIdx.x*4;
    f32x4 v = *(const f32x4*)(row + idx);
#pragma unroll
    for (int e = 0; e < 4; ++e) {
      unsigned j = idx + e;
      unsigned i = (j * 149797u) >> 20;   // j/7
      unsigned k = j - i*7;
      t[k*1024 + i] = f2bf(v[e]);
    }
  }
  __syncthreads();
#pragma unroll
  for (int p = 0; p < 7; ++p) {
    int idx = p*1024 + threadIdx.x*4;
    *(u16x4*)(orow + idx) = *(const u16x4*)(t + idx);
  }
}

// ---------- conv256: 256x256 tile, BK=64, 8-wave, 8-phase counted-vmcnt ----------
// (R3 version — FROZEN: 128 VGPR + 128 AGPR = 256 = the (512,2) cap; any
// register increase spills, per R4. Best measured 266-286 us.)
__global__ __launch_bounds__(512, 2) void conv256(
    const unsigned short* __restrict__ Apad,
    const unsigned short* __restrict__ Wt,
    unsigned short* __restrict__ Ksg, unsigned short* __restrict__ Vsg,
    float* __restrict__ Qp) {
  __shared__ unsigned short As[2][2][8192];
  __shared__ unsigned short Bs[2][2][8192];

  const int tid = threadIdx.x;
  const int w = tid >> 6, l = tid & 63;
  const int wm = w >> 2, wn = w & 3;
  const int l15 = l & 15, lh4 = l >> 4, l7 = l & 7;
  const int chA = ((l7 & 4) | (lh4 ^ (l7 & 3))) << 3;
  const int wOff = w << 9;               // wave-uniform LDS segment (halfwords)
  const int bid = blockIdx.x;
  const int xcd = bid & 7, j = bid >> 3;
  const int ct = j & 7, rt = (xcd << 2) | (j >> 3);

  unsigned aOff[2][2], bOff[2][2];       // [half][i]
#pragma unroll
  for (int i = 0; i < 2; ++i) {
    const int idx = i * 512 + tid;
    const int r = idx >> 3;
    const int clog8 = (((idx & 7) ^ (r & 7)) << 3);
#pragma unroll
    for (int hh = 0; hh < 2; ++hh) {
      const int rg = (rt << 8) + (hh << 7) + r;          // 0..8191
      aOff[hh][i] = ((unsigned)((rg >> 12) * 4102 + (rg & 4095)) << 10) + clog8;
      const int cg = (ct << 8) + (hh << 7) + r;          // 0..2047
      bOff[hh][i] = (unsigned)cg * 7168u + clog8;
    }
  }

  unsigned aRd[4], bRd[2];
#pragma unroll
  for (int fm = 0; fm < 4; ++fm)
    aRd[fm] = (unsigned)(((wm << 6) + (fm << 4) + l15) << 6) + chA;
#pragma unroll
  for (int fn = 0; fn < 2; ++fn)
    bRd[fn] = (unsigned)(((wn << 5) + (fn << 4) + l15) << 6) + chA;

  f32x4 acc[2][2][4][2] = {};
  short8 af[4][2], bfr[2][2];

#define STGA(BUF, HALF, T) do { \
    __builtin_amdgcn_global_load_lds((const AS1 void*)(Apad + aOff[HALF][0] + ((unsigned)(T) << 6)), (AS3 void*)&As[BUF][HALF][wOff], 16, 0, 0); \
    __builtin_amdgcn_global_load_lds((const AS1 void*)(Apad + aOff[HALF][1] + ((unsigned)(T) << 6)), (AS3 void*)&As[BUF][HALF][4096 + wOff], 16, 0, 0); \
  } while (0)
#define STGB(BUF, HALF, T) do { \
    __builtin_amdgcn_global_load_lds((const AS1 void*)(Wt + bOff[HALF][0] + ((unsigned)(T) << 6)), (AS3 void*)&Bs[BUF][HALF][wOff], 16, 0, 0); \
    __builtin_amdgcn_global_load_lds((const AS1 void*)(Wt + bOff[HALF][1] + ((unsigned)(T) << 6)), (AS3 void*)&Bs[BUF][HALF][4096 + wOff], 16, 0, 0); \
  } while (0)
#define LDA(BUF, MQ) do { \
    _Pragma("unroll") for (int fm = 0; fm < 4; ++fm) { \
      af[fm][0] = *(const short8*)&As[BUF][MQ][aRd[fm]]; \
      af[fm][1] = *(const short8*)&As[BUF][MQ][aRd[fm] ^ 32u]; } \
  } while (0)
#define LDB(BUF, NQ) do { \
    _Pragma("unroll") for (int fn = 0; fn < 2; ++fn) { \
      bfr[fn][0] = *(const short8*)&Bs[BUF][NQ][bRd[fn]]; \
      bfr[fn][1] = *(const short8*)&Bs[BUF][NQ][bRd[fn] ^ 32u]; } \
  } while (0)
#define MM(MQ, NQ) do { \
    _Pragma("unroll") for (int ks = 0; ks < 2; ++ks) \
    _Pragma("unroll") for (int fm = 0; fm < 4; ++fm) \
    _Pragma("unroll") for (int fn = 0; fn < 2; ++fn) \
      acc[MQ][NQ][fm][fn] = __builtin_amdgcn_mfma_f32_16x16x32_bf16(af[fm][ks], bfr[fn][ks], acc[MQ][NQ][fm][fn], 0, 0, 0); \
  } while (0)
#define BAR __builtin_amdgcn_s_barrier()
#define LGKM0 asm volatile("s_waitcnt lgkmcnt(0)" ::: "memory")
#define VM6 asm volatile("s_waitcnt vmcnt(6)" ::: "memory")
#define VM0 asm volatile("s_waitcnt vmcnt(0)" ::: "memory")
#define P1 __builtin_amdgcn_s_setprio(1)
#define P0 __builtin_amdgcn_s_setprio(0)

  // Phase ledger: vmcnt(6) at ph4/ph8 keeps 3 half-tiles in flight.
#define RUN_GEMM(NIT) do { \
    STGA(0, 0, 0); STGB(0, 0, 0); STGA(0, 1, 0); STGB(0, 1, 0); \
    STGA(1, 0, 1); STGB(1, 1, 1); STGA(1, 1, 1); \
    VM6; BAR; \
    for (int I = 0; I < (NIT) - 1; ++I) { \
      const int t0 = I * 2; \
      LDA(0, 0); LDB(0, 0); STGB(1, 0, t0 + 1); \
      BAR; LGKM0; P1; MM(0, 0); P0; BAR; \
      LDB(0, 1);            STGA(0, 0, t0 + 2); \
      BAR; LGKM0; P1; MM(0, 1); P0; BAR; \
      LDA(0, 1);            STGB(0, 1, t0 + 2); \
      BAR; LGKM0; P1; MM(1, 1); P0; BAR; \
      LDB(0, 0);            STGA(0, 1, t0 + 2); \
      BAR; LGKM0; P1; MM(1, 0); P0; VM6; BAR; \
      LDA(1, 0); LDB(1, 0); STGB(0, 0, t0 + 2); \
      BAR; LGKM0; P1; MM(0, 0); P0; BAR; \
      LDB(1, 1);            STGA(1, 0, t0 + 3); \
      BAR; LGKM0; P1; MM(0, 1); P0; BAR; \
      LDA(1, 1);            STGB(1, 1, t0 + 3); \
      BAR; LGKM0; P1; MM(1, 1); P0; BAR; \
      LDB(1, 0);            STGA(1, 1, t0 + 3); \
      BAR; LGKM0; P1; MM(1, 0); P0; VM6; BAR; \
    } \
    { \
      LDA(0, 0); LDB(0, 0); STGB(1, 0, ((NIT) - 1) * 2 + 1); \
      BAR; LGKM0; P1; MM(0, 0); P0; BAR; \
      LDB(0, 1); BAR; LGKM0; P1; MM(0, 1); P0; BAR; \
      LDA(0, 1); BAR; LGKM0; P1; MM(1, 1); P0; BAR; \
      LDB(0, 0); BAR; LGKM0; P1; MM(1, 0); P0; VM0; BAR; \
      LDA(1, 0); LDB(1, 0); BAR; LGKM0; P1; MM(0, 0); P0; BAR; \
      LDB(1, 1); BAR; LGKM0; P1; MM(0, 1); P0; BAR; \
      LDA(1, 1); BAR; LGKM0; P1; MM(1, 1); P0; BAR; \
      LDB(1, 0); BAR; LGKM0; P1; MM(1, 0); P0; BAR; \
    } \
  } while (0)

  RUN_GEMM(56);   // 112 K-tiles, K=7168

  // C cell: row = rt*256 + mq*128 + wm*64 + fm*16 + lh4*4 + rr
  //         col = ct*256 + nq*128 + wn*32 + fn*16 + l15
  if (ct < 4) {   // K -> Ksg[bh][kd2][n4096][32]
#pragma unroll
    for (int mq = 0; mq < 2; ++mq)
#pragma unroll
      for (int nq = 0; nq < 2; ++nq) {
        const int h = (ct << 2) + (nq << 1) + (wn >> 1);
        const int kd = wn & 1;
#pragma unroll
        for (int fm = 0; fm < 4; ++fm) {
          const int rbase = (rt << 8) + (mq << 7) + (wm << 6) + (fm << 4) + (lh4 << 2);
          const int b = rbase >> 12, n0 = rbase & 4095;
          const size_t base = ((((size_t)((b * 16 + h) * 2 + kd)) << 12) + n0) << 5;
#pragma unroll
          for (int fn = 0; fn < 2; ++fn) {
            const int d32 = (fn << 4) + l15;
#pragma unroll
            for (int rr = 0; rr < 4; ++rr)
              Ksg[base + ((size_t)rr << 5) + d32] = f2bf(acc[mq][nq][fm][fn][rr]);
          }
        }
      }
  } else {        // V -> Vsg[bh][n>>5][d][n&31]
#pragma unroll
    for (int mq = 0; mq < 2; ++mq)
#pragma unroll
      for (int nq = 0; nq < 2; ++nq) {
        const int h = ((ct - 4) << 2) + (nq << 1) + (wn >> 1);
        const int dhi = (wn & 1) << 5;
#pragma unroll
        for (int fm = 0; fm < 4; ++fm) {
          const int rbase = (rt << 8) + (mq << 7) + (wm << 6) + (fm << 4) + (lh4 << 2);
          const int b = rbase >> 12, n = rbase & 4095;
#pragma unroll
          for (int fn = 0; fn < 2; ++fn) {
            const int d = dhi + (fn << 4) + l15;
            const size_t rowbase =
                ((((((size_t)(b * 16 + h)) << 7) + (n >> 5)) << 6) + d) * 32 + (n & 31);
            u16x4 pv;
#pragma unroll
            for (int rr = 0; rr < 4; ++rr) pv[rr] = f2bf(acc[mq][nq][fm][fn][rr]);
            *(u16x4*)(Vsg + rowbase) = pv;
          }
        }
      }
  }

  // ---- part 2: Q partial (K-chunk kc of 8, K=896 = 14 tiles) ----
  const int qct = j & 3, qrt = j >> 2, kc = xcd;
  const unsigned kbase = (unsigned)kc * 896u;
#pragma unroll
  for (int i = 0; i < 2; ++i) {
    const int idx = i * 512 + tid;
    const int r = idx >> 3;
    const int clog8 = (((idx & 7) ^ (r & 7)) << 3);
#pragma unroll
    for (int hh = 0; hh < 2; ++hh) {
      const int rg = (qrt << 8) + (hh << 7) + r;         // 0..2047
      aOff[hh][i] = ((unsigned)((rg >> 10) * 4102 + ((rg & 1023) << 2)) << 10) + clog8 + kbase;
      const int cg = 2048 + (qct << 8) + (hh << 7) + r;  // Wq rows in Wt
      bOff[hh][i] = (unsigned)cg * 7168u + clog8 + kbase;
    }
  }
#pragma unroll
  for (int mq = 0; mq < 2; ++mq)
#pragma unroll
    for (int nq = 0; nq < 2; ++nq)
#pragma unroll
      for (int fm = 0; fm < 4; ++fm)
#pragma unroll
        for (int fn = 0; fn < 2; ++fn)
          acc[mq][nq][fm][fn] = (f32x4){0.f, 0.f, 0.f, 0.f};

  RUN_GEMM(7);

  // plain coalesced f32 stores into this chunk's private slice (no atomics)
  float* Qc = Qp + ((size_t)kc << 21);
#pragma unroll
  for (int mq = 0; mq < 2; ++mq)
#pragma unroll
    for (int nq = 0; nq < 2; ++nq)
#pragma unroll
      for (int fm = 0; fm < 4; ++fm) {
        const int rq = (qrt << 8) + (mq << 7) + (wm << 6) + (fm << 4) + (lh4 << 2);
#pragma unroll
        for (int fn = 0; fn < 2; ++fn) {
          const int cq = (qct << 8) + (nq << 7) + (wn << 5) + (fn << 4) + l15;
#pragma unroll
          for (int rr = 0; rr < 4; ++rr)
            Qc[(((size_t)(rq + rr)) << 10) + cq] = acc[mq][nq][fm][fn][rr];
        }
      }
#undef STGA
#undef STGB
#undef LDA
#undef LDB
#undef MM
#undef BAR
#undef LGKM0
#undef VM6
#undef VM0
#undef P1
#undef P0
#undef RUN_GEMM
}

// ---------- reduce 8 Qp chunks -> Qf (f32) + Qsg (bf16 swizzled) ----------
__global__ __launch_bounds__(256) void qfinal(
    const float* __restrict__ Qp, float* __restrict__ Qf,
    unsigned short* __restrict__ Qsg) {
  const int rq = blockIdx.x;             // 0..2047
  const int b = rq >> 10, m = rq & 1023;
  const int c = threadIdx.x << 2;
  f32x4 v = {0.f, 0.f, 0.f, 0.f};
#pragma unroll
  for (int kc = 0; kc < 8; ++kc) {
    f32x4 p = *(const f32x4*)(Qp + ((size_t)kc << 21) + ((size_t)rq << 10) + c);
    v[0] += p[0]; v[1] += p[1]; v[2] += p[2]; v[3] += p[3];
  }
  *(f32x4*)(Qf + ((size_t)rq << 10) + c) = v;
  const int h = c >> 6, kd = (c >> 5) & 1, d32 = c & 31;
  u16x4 o;
#pragma unroll
  for (int e = 0; e < 4; ++e) o[e] = f2bf(v[e]);
  *(u16x4*)(Qsg + ((((size_t)((b * 16 + h) * 2 + kd)) << 10) + m) * 32 + d32) = o;
}

// ---------- Flash attention v4: stagger + V direct global->reg ----------
// V skips LDS: the staged path's net lane mapping (gload_lds lane-linear dest
// composed with lsw source swizzle and ch read swizzle) collapses to
//   vfrag[kn][dt](lane) = VgT[(it*4+kn)*2048 + (dt*16+lc)*32 + ((quad^l3^(lc&3))<<3)]
// — bit-identical data, still a 64x16B coalesced permutation of 1KB.
// Loads issue after PV consumes old vfrag (WAR), overlap QK+softmax, retired
// by the per-iter vmcnt(0). Q fragments hoisted (read once). su reduce deferred.
__global__ __launch_bounds__(512) void attn_kernel(
    const unsigned short* __restrict__ Ksg, const unsigned short* __restrict__ Vsg,
    const unsigned short* __restrict__ Qsg, const float* __restrict__ Qf,
    float* __restrict__ out) {
  __shared__ unsigned short Ks[2][8192];   // [kd2][n128][32] swizzled
  __shared__ unsigned short Qs[8192];      // [kd2][m128][32] swizzled
  __shared__ unsigned short Ps[2][17408];  // double-buffered, per-wave 16m x 136
  const int tid = threadIdx.x, w = tid >> 6, l = tid & 63;
  const int g = blockIdx.x;               // 256 blocks
  const int bh = (g & 7) + (((g >> 3) & 3) << 3);
  const int qt = g >> 5;                  // 0..7
  const int b = bh >> 4, h = bh & 15;
  const int m0 = qt << 7;                 // 128 q rows per block
  const int quad = l >> 4, lc = l & 15, l3 = l & 3;
  const float C = 0.18033688011112042f;   // log2(e)/8
  const int lsw = (l & 60) | ((l ^ (l >> 2)) & 3);
  const int ch = (quad ^ l3) << 3;
  const int vch = (quad ^ l3 ^ (lc & 3)) << 3;

  const unsigned short* KgT = Ksg + ((size_t)bh << 18);
  const unsigned short* VgT = Vsg + ((size_t)bh << 18);
  const unsigned short* QgT = Qsg + ((size_t)bh << 16);

#pragma unroll
  for (int p = 0; p < 2; ++p) {
    int t = (w << 1) + p;                 // 0..15
    int kd = t >> 3, ml = (t & 7) << 4;
    __builtin_amdgcn_global_load_lds(
        (const AS1 void*)(QgT + ((size_t)((kd << 10) + m0 + ml) << 5) + lsw*8),
        (AS3 void*)(Qs + (t << 9)), 16, 0, 0);
  }

#define STAGE_K(BUF, N0) do { \
    _Pragma("unroll") for (int p = 0; p < 2; ++p) { \
      int t = (w << 1) + p; \
      __builtin_amdgcn_global_load_lds( \
          (const AS1 void*)(KgT + ((size_t)(((t >> 3) << 12) + (N0) + ((t & 7) << 4)) << 5) + lsw*8), \
          (AS3 void*)(Ks[BUF] + (t << 9)), 16, 0, 0); \
    } \
  } while (0)

  float su_acc = 0.f;
  f32x4 oacc[4] = {};
  short8 vfrag[4][4];                     // [kn][dt] — V(it) held across iters

  STAGE_K(0, 0);
  asm volatile("s_waitcnt vmcnt(0)" ::: "memory");
  __builtin_amdgcn_s_barrier();

  // Q fragments: loop-invariant, read once
  short8 bq[2];
#pragma unroll
  for (int k = 0; k < 2; ++k)
    bq[k] = *(const short8*)(Qs + (k << 12) + ((w<<4) + lc)*32 + ch);

  for (int it = 0; it < 32; ++it) {
    const int cur = it & 1;
    const unsigned short* Kc = Ks[cur];
    if (it < 31) STAGE_K(cur ^ 1, (it + 1) << 7);

    // ---- PV(it-1): vfrag regs x Ps[prev] (per-wave private) ----
    if (it > 0) {
      unsigned short* Pp = Ps[cur ^ 1] + w*2176;
#pragma unroll
      for (int kn = 0; kn < 4; ++kn) {
        short8 bp = *(const short8*)(Pp + lc*136 + (kn<<5) + (quad<<3));
#pragma unroll
        for (int dt = 0; dt < 4; ++dt)
          oacc[dt] = __builtin_amdgcn_mfma_f32_16x16x32_bf16(vfrag[kn][dt], bp, oacc[dt], 0, 0, 0);
      }
    }

    // ---- V(it) -> registers, direct from global (overlaps QK+softmax) ----
    {
      const unsigned short* Vb = VgT + ((size_t)it << 13);
#pragma unroll
      for (int kn = 0; kn < 4; ++kn)
#pragma unroll
        for (int dt = 0; dt < 4; ++dt)
          vfrag[kn][dt] = *(const short8*)(Vb + (kn << 11) + ((dt<<4) + lc)*32 + vch);
    }

    // ---- QK(it) ----
    short8 ak[8][2];
#pragma unroll
    for (int k = 0; k < 2; ++k)
#pragma unroll
      for (int ni = 0; ni < 8; ++ni)
        ak[ni][k] = *(const short8*)(Kc + (k << 12) + ((ni<<4) + lc)*32 + ch);

    f32x4 sv[8] = {};
#pragma unroll
    for (int k = 0; k < 2; ++k)
#pragma unroll
      for (int ni = 0; ni < 8; ++ni)
        sv[ni] = __builtin_amdgcn_mfma_f32_16x16x32_bf16(ak[ni][k], bq[k], sv[ni], 0, 0, 0);

    // ---- softmax(it) -> Ps[cur] ----
    unsigned short* Pw = Ps[cur] + w*2176;
#pragma unroll
    for (int ni = 0; ni < 8; ++ni) {
      u16x4 pv;
#pragma unroll
      for (int rr = 0; rr < 4; ++rr) {
        float pp = __builtin_amdgcn_exp2f(sv[ni][rr] * C);
        su_acc += pp;
        pv[rr] = f2bf_fast(pp);
      }
      *(u16x4*)(Pw + lc*136 + (ni<<4) + (quad<<2)) = pv;
    }

    asm volatile("s_waitcnt vmcnt(0)" ::: "memory");
    __builtin_amdgcn_s_barrier();
  }

  // ---- final PV(31) ----
  {
    unsigned short* Pp = Ps[1] + w*2176;
#pragma unroll
    for (int kn = 0; kn < 4; ++kn) {
      short8 bp = *(const short8*)(Pp + lc*136 + (kn<<5) + (quad<<3));
#pragma unroll
      for (int dt = 0; dt < 4; ++dt)
        oacc[dt] = __builtin_amdgcn_mfma_f32_16x16x32_bf16(vfrag[kn][dt], bp, oacc[dt], 0, 0, 0);
    }
  }
#undef STAGE_K

  // deferred cross-lane softmax-denominator reduction
  su_acc += __shfl_xor(su_acc, 16, 64);
  su_acc += __shfl_xor(su_acc, 32, 64);
  float invl = 1.0f / su_acc;
  int m = m0 + (w<<4) + lc;
#pragma unroll
  for (int dt = 0; dt < 4; ++dt) {
    int d = (dt<<4) + (quad<<2);
    size_t off = (((size_t)(b << 10) + m) << 10) + (h << 6) + d;
    f32x4 qv = *(const f32x4*)(Qf + off);
    f32x4 ov;
#pragma unroll
    for (int rr = 0; rr < 4; ++rr) ov[rr] = oacc[dt][rr]*invl + qv[rr];
    *(f32x4*)(out + off) = ov;
  }
}

extern "C" void kernel_launch(void* const* d_in, const int* in_sizes, int n_in,
                              void* d_out, int out_size, void* d_ws, size_t ws_size,
                              hipStream_t stream) {
  const float* x  = (const float*)d_in[0];
  const float* lw = (const float*)d_in[1];
  const float* lb = (const float*)d_in[2];
  const float* Wk = (const float*)d_in[3];
  const float* Wv = (const float*)d_in[4];
  const float* Wq = (const float*)d_in[5];
  float* out = (float*)d_out;

  char* ws = (char*)d_ws;
  size_t off = 0;
  unsigned short* xpad = (unsigned short*)(ws + off); off += (size_t)2*4102*1024*2;
  unsigned short* Wt   = (unsigned short*)(ws + off); off += (size_t)3072*7168*2;
  unsigned short* Ksg  = (unsigned short*)(ws + off); off += (size_t)32*2*4096*32*2;
  unsigned short* Vsg  = (unsigned short*)(ws + off); off += (size_t)32*128*64*32*2;
  unsigned short* Qsg  = (unsigned short*)(ws + off); off += (size_t)32*2*1024*32*2;
  float*          Qf   = (float*)(ws + off);          off += (size_t)2048*1024*4;
  float*          Qp   = (float*)(ws + off);          off += (size_t)8*2048*1024*4;

  for (int b = 0; b < 2; ++b) {
    hipMemsetAsync(xpad + (size_t)b*4102*1024, 0, 3*1024*2, stream);
    hipMemsetAsync(xpad + ((size_t)b*4102 + 4099)*1024, 0, 3*1024*2, stream);
  }
  ln_kernel<<<dim3(8192), dim3(256), 0, stream>>>(x, lw, lb, xpad);
  repack_kernel<<<dim3(1024, 3), dim3(256), 0, stream>>>(Wk, Wv, Wq, Wt);
  conv256<<<dim3(256), dim3(512), 0, stream>>>(xpad, Wt, Ksg, Vsg, Qp);
  qfinal<<<dim3(2048), dim3(256), 0, stream>>>(Qp, Qf, Qsg);
  attn_kernel<<<dim3(256), dim3(512), 0, stream>>>(Ksg, Vsg, Qsg, Qf, out);
}

// Round 8
// 476.844 us; speedup vs baseline: 1.0424x; 1.0424x over previous
//
#include <hip/hip_runtime.h>

typedef __attribute__((ext_vector_type(4))) float f32x4;
typedef __attribute__((ext_vector_type(8))) short short8;
typedef __attribute__((ext_vector_type(4))) unsigned short u16x4;

#define AS1 __attribute__((address_space(1)))
#define AS3 __attribute__((address_space(3)))

__device__ __forceinline__ unsigned short f2bf(float f) {
  unsigned u = __float_as_uint(f);
  return (unsigned short)((u + 0x7FFFu + ((u >> 16) & 1u)) >> 16);
}
__device__ __forceinline__ unsigned short f2bf_fast(float f) {
  return (unsigned short)((__float_as_uint(f) + 0x8000u) >> 16);
}

// ---------- LayerNorm fp32 -> bf16 into zero-padded (B, 3+N+3, D) ----------
__global__ __launch_bounds__(256) void ln_kernel(
    const float* __restrict__ x, const float* __restrict__ lw,
    const float* __restrict__ lb, unsigned short* __restrict__ xpad) {
  __shared__ float red[8];
  int row = blockIdx.x;                  // 0..8191
  int b = row >> 12, n = row & 4095;
  const float* xr = x + (size_t)row * 1024;
  int c = threadIdx.x * 4;
  f32x4 v = *(const f32x4*)(xr + c);
  float s = v[0] + v[1] + v[2] + v[3];
  float sq = v[0]*v[0] + v[1]*v[1] + v[2]*v[2] + v[3]*v[3];
#pragma unroll
  for (int off = 32; off; off >>= 1) {
    s  += __shfl_xor(s, off, 64);
    sq += __shfl_xor(sq, off, 64);
  }
  int w = threadIdx.x >> 6;
  if ((threadIdx.x & 63) == 0) { red[w*2] = s; red[w*2+1] = sq; }
  __syncthreads();
  float S  = red[0]+red[2]+red[4]+red[6];
  float SQ = red[1]+red[3]+red[5]+red[7];
  float mean = S * (1.0f/1024.0f);
  float var  = SQ * (1.0f/1024.0f) - mean*mean;
  float rstd = rsqrtf(var + 1e-5f);
  f32x4 wv = *(const f32x4*)(lw + c);
  f32x4 bv = *(const f32x4*)(lb + c);
  u16x4 o;
#pragma unroll
  for (int r = 0; r < 4; ++r) o[r] = f2bf((v[r]-mean)*rstd*wv[r] + bv[r]);
  *(u16x4*)(xpad + (((size_t)(b*4102 + n + 3)) << 10) + c) = o;
}

// ---------- Repack W (O,I,K) fp32 -> Wt rows (kk=k*1024+i) bf16 ----------
__global__ __launch_bounds__(256) void repack_kernel(
    const float* __restrict__ Wk, const float* __restrict__ Wv,
    const float* __restrict__ Wq, unsigned short* __restrict__ Wt) {
  __shared__ unsigned short t[7168];
  const float* W = (blockIdx.y == 0) ? Wk : (blockIdx.y == 1) ? Wv : Wq;
  int o = blockIdx.x;
  const float* row = W + (size_t)o * 7168;
  unsigned short* orow = Wt + ((size_t)(blockIdx.y * 1024 + o)) * 7168;
#pragma unroll
  for (int p = 0; p < 7; ++p) {
    int idx = p*1024 + threadIdx.x*4;
    f32x4 v = *(const f32x4*)(row + idx);
#pragma unroll
    for (int e = 0; e < 4; ++e) {
      unsigned j = idx + e;
      unsigned i = (j * 149797u) >> 20;   // j/7
      unsigned k = j - i*7;
      t[k*1024 + i] = f2bf(v[e]);
    }
  }
  __syncthreads();
#pragma unroll
  for (int p = 0; p < 7; ++p) {
    int idx = p*1024 + threadIdx.x*4;
    *(u16x4*)(orow + idx) = *(const u16x4*)(t + idx);
  }
}

// ---------- conv256: 256x256 tile, BK=64, 8-wave, 8-phase counted-vmcnt ----------
// (R3 version — FROZEN: 128 VGPR + 128 AGPR = 256 = the (512,2) cap.)
__global__ __launch_bounds__(512, 2) void conv256(
    const unsigned short* __restrict__ Apad,
    const unsigned short* __restrict__ Wt,
    unsigned short* __restrict__ Ksg, unsigned short* __restrict__ Vsg,
    float* __restrict__ Qp) {
  __shared__ unsigned short As[2][2][8192];
  __shared__ unsigned short Bs[2][2][8192];

  const int tid = threadIdx.x;
  const int w = tid >> 6, l = tid & 63;
  const int wm = w >> 2, wn = w & 3;
  const int l15 = l & 15, lh4 = l >> 4, l7 = l & 7;
  const int chA = ((l7 & 4) | (lh4 ^ (l7 & 3))) << 3;
  const int wOff = w << 9;               // wave-uniform LDS segment (halfwords)
  const int bid = blockIdx.x;
  const int xcd = bid & 7, j = bid >> 3;
  const int ct = j & 7, rt = (xcd << 2) | (j >> 3);

  unsigned aOff[2][2], bOff[2][2];       // [half][i]
#pragma unroll
  for (int i = 0; i < 2; ++i) {
    const int idx = i * 512 + tid;
    const int r = idx >> 3;
    const int clog8 = (((idx & 7) ^ (r & 7)) << 3);
#pragma unroll
    for (int hh = 0; hh < 2; ++hh) {
      const int rg = (rt << 8) + (hh << 7) + r;          // 0..8191
      aOff[hh][i] = ((unsigned)((rg >> 12) * 4102 + (rg & 4095)) << 10) + clog8;
      const int cg = (ct << 8) + (hh << 7) + r;          // 0..2047
      bOff[hh][i] = (unsigned)cg * 7168u + clog8;
    }
  }

  unsigned aRd[4], bRd[2];
#pragma unroll
  for (int fm = 0; fm < 4; ++fm)
    aRd[fm] = (unsigned)(((wm << 6) + (fm << 4) + l15) << 6) + chA;
#pragma unroll
  for (int fn = 0; fn < 2; ++fn)
    bRd[fn] = (unsigned)(((wn << 5) + (fn << 4) + l15) << 6) + chA;

  f32x4 acc[2][2][4][2] = {};
  short8 af[4][2], bfr[2][2];

#define STGA(BUF, HALF, T) do { \
    __builtin_amdgcn_global_load_lds((const AS1 void*)(Apad + aOff[HALF][0] + ((unsigned)(T) << 6)), (AS3 void*)&As[BUF][HALF][wOff], 16, 0, 0); \
    __builtin_amdgcn_global_load_lds((const AS1 void*)(Apad + aOff[HALF][1] + ((unsigned)(T) << 6)), (AS3 void*)&As[BUF][HALF][4096 + wOff], 16, 0, 0); \
  } while (0)
#define STGB(BUF, HALF, T) do { \
    __builtin_amdgcn_global_load_lds((const AS1 void*)(Wt + bOff[HALF][0] + ((unsigned)(T) << 6)), (AS3 void*)&Bs[BUF][HALF][wOff], 16, 0, 0); \
    __builtin_amdgcn_global_load_lds((const AS1 void*)(Wt + bOff[HALF][1] + ((unsigned)(T) << 6)), (AS3 void*)&Bs[BUF][HALF][4096 + wOff], 16, 0, 0); \
  } while (0)
#define LDA(BUF, MQ) do { \
    _Pragma("unroll") for (int fm = 0; fm < 4; ++fm) { \
      af[fm][0] = *(const short8*)&As[BUF][MQ][aRd[fm]]; \
      af[fm][1] = *(const short8*)&As[BUF][MQ][aRd[fm] ^ 32u]; } \
  } while (0)
#define LDB(BUF, NQ) do { \
    _Pragma("unroll") for (int fn = 0; fn < 2; ++fn) { \
      bfr[fn][0] = *(const short8*)&Bs[BUF][NQ][bRd[fn]]; \
      bfr[fn][1] = *(const short8*)&Bs[BUF][NQ][bRd[fn] ^ 32u]; } \
  } while (0)
#define MM(MQ, NQ) do { \
    _Pragma("unroll") for (int ks = 0; ks < 2; ++ks) \
    _Pragma("unroll") for (int fm = 0; fm < 4; ++fm) \
    _Pragma("unroll") for (int fn = 0; fn < 2; ++fn) \
      acc[MQ][NQ][fm][fn] = __builtin_amdgcn_mfma_f32_16x16x32_bf16(af[fm][ks], bfr[fn][ks], acc[MQ][NQ][fm][fn], 0, 0, 0); \
  } while (0)
#define BAR __builtin_amdgcn_s_barrier()
#define LGKM0 asm volatile("s_waitcnt lgkmcnt(0)" ::: "memory")
#define VM6 asm volatile("s_waitcnt vmcnt(6)" ::: "memory")
#define VM0 asm volatile("s_waitcnt vmcnt(0)" ::: "memory")
#define P1 __builtin_amdgcn_s_setprio(1)
#define P0 __builtin_amdgcn_s_setprio(0)

  // Phase ledger: vmcnt(6) at ph4/ph8 keeps 3 half-tiles in flight.
#define RUN_GEMM(NIT) do { \
    STGA(0, 0, 0); STGB(0, 0, 0); STGA(0, 1, 0); STGB(0, 1, 0); \
    STGA(1, 0, 1); STGB(1, 1, 1); STGA(1, 1, 1); \
    VM6; BAR; \
    for (int I = 0; I < (NIT) - 1; ++I) { \
      const int t0 = I * 2; \
      LDA(0, 0); LDB(0, 0); STGB(1, 0, t0 + 1); \
      BAR; LGKM0; P1; MM(0, 0); P0; BAR; \
      LDB(0, 1);            STGA(0, 0, t0 + 2); \
      BAR; LGKM0; P1; MM(0, 1); P0; BAR; \
      LDA(0, 1);            STGB(0, 1, t0 + 2); \
      BAR; LGKM0; P1; MM(1, 1); P0; BAR; \
      LDB(0, 0);            STGA(0, 1, t0 + 2); \
      BAR; LGKM0; P1; MM(1, 0); P0; VM6; BAR; \
      LDA(1, 0); LDB(1, 0); STGB(0, 0, t0 + 2); \
      BAR; LGKM0; P1; MM(0, 0); P0; BAR; \
      LDB(1, 1);            STGA(1, 0, t0 + 3); \
      BAR; LGKM0; P1; MM(0, 1); P0; BAR; \
      LDA(1, 1);            STGB(1, 1, t0 + 3); \
      BAR; LGKM0; P1; MM(1, 1); P0; BAR; \
      LDB(1, 0);            STGA(1, 1, t0 + 3); \
      BAR; LGKM0; P1; MM(1, 0); P0; VM6; BAR; \
    } \
    { \
      LDA(0, 0); LDB(0, 0); STGB(1, 0, ((NIT) - 1) * 2 + 1); \
      BAR; LGKM0; P1; MM(0, 0); P0; BAR; \
      LDB(0, 1); BAR; LGKM0; P1; MM(0, 1); P0; BAR; \
      LDA(0, 1); BAR; LGKM0; P1; MM(1, 1); P0; BAR; \
      LDB(0, 0); BAR; LGKM0; P1; MM(1, 0); P0; VM0; BAR; \
      LDA(1, 0); LDB(1, 0); BAR; LGKM0; P1; MM(0, 0); P0; BAR; \
      LDB(1, 1); BAR; LGKM0; P1; MM(0, 1); P0; BAR; \
      LDA(1, 1); BAR; LGKM0; P1; MM(1, 1); P0; BAR; \
      LDB(1, 0); BAR; LGKM0; P1; MM(1, 0); P0; BAR; \
    } \
  } while (0)

  RUN_GEMM(56);   // 112 K-tiles, K=7168

  // C cell: row = rt*256 + mq*128 + wm*64 + fm*16 + lh4*4 + rr
  //         col = ct*256 + nq*128 + wn*32 + fn*16 + l15
  if (ct < 4) {   // K -> Ksg[bh][kd2][n4096][32]
#pragma unroll
    for (int mq = 0; mq < 2; ++mq)
#pragma unroll
      for (int nq = 0; nq < 2; ++nq) {
        const int h = (ct << 2) + (nq << 1) + (wn >> 1);
        const int kd = wn & 1;
#pragma unroll
        for (int fm = 0; fm < 4; ++fm) {
          const int rbase = (rt << 8) + (mq << 7) + (wm << 6) + (fm << 4) + (lh4 << 2);
          const int b = rbase >> 12, n0 = rbase & 4095;
          const size_t base = ((((size_t)((b * 16 + h) * 2 + kd)) << 12) + n0) << 5;
#pragma unroll
          for (int fn = 0; fn < 2; ++fn) {
            const int d32 = (fn << 4) + l15;
#pragma unroll
            for (int rr = 0; rr < 4; ++rr)
              Ksg[base + ((size_t)rr << 5) + d32] = f2bf(acc[mq][nq][fm][fn][rr]);
          }
        }
      }
  } else {        // V -> Vsg[bh][n>>5][d][n&31]
#pragma unroll
    for (int mq = 0; mq < 2; ++mq)
#pragma unroll
      for (int nq = 0; nq < 2; ++nq) {
        const int h = ((ct - 4) << 2) + (nq << 1) + (wn >> 1);
        const int dhi = (wn & 1) << 5;
#pragma unroll
        for (int fm = 0; fm < 4; ++fm) {
          const int rbase = (rt << 8) + (mq << 7) + (wm << 6) + (fm << 4) + (lh4 << 2);
          const int b = rbase >> 12, n = rbase & 4095;
#pragma unroll
          for (int fn = 0; fn < 2; ++fn) {
            const int d = dhi + (fn << 4) + l15;
            const size_t rowbase =
                ((((((size_t)(b * 16 + h)) << 7) + (n >> 5)) << 6) + d) * 32 + (n & 31);
            u16x4 pv;
#pragma unroll
            for (int rr = 0; rr < 4; ++rr) pv[rr] = f2bf(acc[mq][nq][fm][fn][rr]);
            *(u16x4*)(Vsg + rowbase) = pv;
          }
        }
      }
  }

  // ---- part 2: Q partial (K-chunk kc of 8, K=896 = 14 tiles) ----
  const int qct = j & 3, qrt = j >> 2, kc = xcd;
  const unsigned kbase = (unsigned)kc * 896u;
#pragma unroll
  for (int i = 0; i < 2; ++i) {
    const int idx = i * 512 + tid;
    const int r = idx >> 3;
    const int clog8 = (((idx & 7) ^ (r & 7)) << 3);
#pragma unroll
    for (int hh = 0; hh < 2; ++hh) {
      const int rg = (qrt << 8) + (hh << 7) + r;         // 0..2047
      aOff[hh][i] = ((unsigned)((rg >> 10) * 4102 + ((rg & 1023) << 2)) << 10) + clog8 + kbase;
      const int cg = 2048 + (qct << 8) + (hh << 7) + r;  // Wq rows in Wt
      bOff[hh][i] = (unsigned)cg * 7168u + clog8 + kbase;
    }
  }
#pragma unroll
  for (int mq = 0; mq < 2; ++mq)
#pragma unroll
    for (int nq = 0; nq < 2; ++nq)
#pragma unroll
      for (int fm = 0; fm < 4; ++fm)
#pragma unroll
        for (int fn = 0; fn < 2; ++fn)
          acc[mq][nq][fm][fn] = (f32x4){0.f, 0.f, 0.f, 0.f};

  RUN_GEMM(7);

  // plain coalesced f32 stores into this chunk's private slice (no atomics)
  float* Qc = Qp + ((size_t)kc << 21);
#pragma unroll
  for (int mq = 0; mq < 2; ++mq)
#pragma unroll
    for (int nq = 0; nq < 2; ++nq)
#pragma unroll
      for (int fm = 0; fm < 4; ++fm) {
        const int rq = (qrt << 8) + (mq << 7) + (wm << 6) + (fm << 4) + (lh4 << 2);
#pragma unroll
        for (int fn = 0; fn < 2; ++fn) {
          const int cq = (qct << 8) + (nq << 7) + (wn << 5) + (fn << 4) + l15;
#pragma unroll
          for (int rr = 0; rr < 4; ++rr)
            Qc[(((size_t)(rq + rr)) << 10) + cq] = acc[mq][nq][fm][fn][rr];
        }
      }
#undef STGA
#undef STGB
#undef LDA
#undef LDB
#undef MM
#undef BAR
#undef LGKM0
#undef VM6
#undef VM0
#undef P1
#undef P0
#undef RUN_GEMM
}

// ---------- reduce 8 Qp chunks -> Qf (f32) + Qsg (bf16 swizzled) ----------
__global__ __launch_bounds__(256) void qfinal(
    const float* __restrict__ Qp, float* __restrict__ Qf,
    unsigned short* __restrict__ Qsg) {
  const int rq = blockIdx.x;             // 0..2047
  const int b = rq >> 10, m = rq & 1023;
  const int c = threadIdx.x << 2;
  f32x4 v = {0.f, 0.f, 0.f, 0.f};
#pragma unroll
  for (int kc = 0; kc < 8; ++kc) {
    f32x4 p = *(const f32x4*)(Qp + ((size_t)kc << 21) + ((size_t)rq << 10) + c);
    v[0] += p[0]; v[1] += p[1]; v[2] += p[2]; v[3] += p[3];
  }
  *(f32x4*)(Qf + ((size_t)rq << 10) + c) = v;
  const int h = c >> 6, kd = (c >> 5) & 1, d32 = c & 31;
  u16x4 o;
#pragma unroll
  for (int e = 0; e < 4; ++e) o[e] = f2bf(v[e]);
  *(u16x4*)(Qsg + ((((size_t)((b * 16 + h) * 2 + kd)) << 10) + m) * 32 + d32) = o;
}

// ---------- Flash attention v5: v3 stagger (K+V LDS-staged) + bq hoist +
// deferred su + T5 setprio around MFMA clusters.
// RULE (R6 lesson): K/V must stay LDS-staged — per-wave global reads of shared
// tiles multiply traffic by the wave count (v4: 8x V traffic, +40 us).
// LAUNCH: grid=256 blocks, block=512 threads (8 waves). R7 crashed on a
// swapped launch config — keep <<<dim3(256), dim3(512)>>>.
__global__ __launch_bounds__(512) void attn_kernel(
    const unsigned short* __restrict__ Ksg, const unsigned short* __restrict__ Vsg,
    const unsigned short* __restrict__ Qsg, const float* __restrict__ Qf,
    float* __restrict__ out) {
  __shared__ unsigned short Ks[2][8192];   // [kd2][n128][32] swizzled
  __shared__ unsigned short Vs[2][8192];   // [kn4][d64][32] swizzled
  __shared__ unsigned short Qs[8192];      // [kd2][m128][32] swizzled
  __shared__ unsigned short Ps[2][17408];  // double-buffered, per-wave 16m x 136
  const int tid = threadIdx.x, w = tid >> 6, l = tid & 63;
  const int g = blockIdx.x;               // 256 blocks
  const int bh = (g & 7) + (((g >> 3) & 3) << 3);
  const int qt = g >> 5;                  // 0..7
  const int b = bh >> 4, h = bh & 15;
  const int m0 = qt << 7;                 // 128 q rows per block
  const int quad = l >> 4, lc = l & 15, l3 = l & 3;
  const float C = 0.18033688011112042f;   // log2(e)/8
  const int lsw = (l & 60) | ((l ^ (l >> 2)) & 3);
  const int ch = (quad ^ l3) << 3;

  const unsigned short* KgT = Ksg + ((size_t)bh << 18);
  const unsigned short* VgT = Vsg + ((size_t)bh << 18);
  const unsigned short* QgT = Qsg + ((size_t)bh << 16);

#pragma unroll
  for (int p = 0; p < 2; ++p) {
    int t = (w << 1) + p;                 // 0..15
    int kd = t >> 3, ml = (t & 7) << 4;
    __builtin_amdgcn_global_load_lds(
        (const AS1 void*)(QgT + ((size_t)((kd << 10) + m0 + ml) << 5) + lsw*8),
        (AS3 void*)(Qs + (t << 9)), 16, 0, 0);
  }

#define STAGE_KV(BUF, N0) do { \
    _Pragma("unroll") for (int p = 0; p < 2; ++p) { \
      int t = (w << 1) + p; \
      __builtin_amdgcn_global_load_lds( \
          (const AS1 void*)(KgT + ((size_t)(((t >> 3) << 12) + (N0) + ((t & 7) << 4)) << 5) + lsw*8), \
          (AS3 void*)(Ks[BUF] + (t << 9)), 16, 0, 0); \
      __builtin_amdgcn_global_load_lds( \
          (const AS1 void*)(VgT + ((size_t)(((((N0) >> 5) + (t >> 2)) << 6) + ((t & 3) << 4)) << 5) + lsw*8), \
          (AS3 void*)(Vs[BUF] + (t << 9)), 16, 0, 0); \
    } \
  } while (0)

  float su_acc = 0.f;
  f32x4 oacc[4] = {};
  short8 vfrag[4][4];                     // [kn][dt] — V(it) held across iters

  STAGE_KV(0, 0);
  asm volatile("s_waitcnt vmcnt(0)" ::: "memory");
  __builtin_amdgcn_s_barrier();

  // Q fragments: loop-invariant, read once
  short8 bq[2];
#pragma unroll
  for (int k = 0; k < 2; ++k)
    bq[k] = *(const short8*)(Qs + (k << 12) + ((w<<4) + lc)*32 + ch);

  for (int it = 0; it < 32; ++it) {
    const int cur = it & 1;
    const unsigned short* Kc = Ks[cur];
    const unsigned short* Vc = Vs[cur];
    if (it < 31) STAGE_KV(cur ^ 1, (it + 1) << 7);

    // ---- PV(it-1): vfrag regs x Ps[prev] (per-wave private) ----
    if (it > 0) {
      unsigned short* Pp = Ps[cur ^ 1] + w*2176;
      __builtin_amdgcn_s_setprio(1);
#pragma unroll
      for (int kn = 0; kn < 4; ++kn) {
        short8 bp = *(const short8*)(Pp + lc*136 + (kn<<5) + (quad<<3));
#pragma unroll
        for (int dt = 0; dt < 4; ++dt)
          oacc[dt] = __builtin_amdgcn_mfma_f32_16x16x32_bf16(vfrag[kn][dt], bp, oacc[dt], 0, 0, 0);
      }
      __builtin_amdgcn_s_setprio(0);
    }

    // ---- QK(it) ----
    short8 ak[8][2];
#pragma unroll
    for (int k = 0; k < 2; ++k)
#pragma unroll
      for (int ni = 0; ni < 8; ++ni)
        ak[ni][k] = *(const short8*)(Kc + (k << 12) + ((ni<<4) + lc)*32 + ch);

    f32x4 sv[8] = {};
    __builtin_amdgcn_s_setprio(1);
#pragma unroll
    for (int k = 0; k < 2; ++k)
#pragma unroll
      for (int ni = 0; ni < 8; ++ni)
        sv[ni] = __builtin_amdgcn_mfma_f32_16x16x32_bf16(ak[ni][k], bq[k], sv[ni], 0, 0, 0);
    __builtin_amdgcn_s_setprio(0);

    // ---- V(it) -> registers (frees buf^1 for next stage before any barrier) ----
#pragma unroll
    for (int kn = 0; kn < 4; ++kn)
#pragma unroll
      for (int dt = 0; dt < 4; ++dt)
        vfrag[kn][dt] = *(const short8*)(Vc + (kn << 11) + ((dt<<4) + lc)*32 + ch);

    // ---- softmax(it) -> Ps[cur] ----
    unsigned short* Pw = Ps[cur] + w*2176;
#pragma unroll
    for (int ni = 0; ni < 8; ++ni) {
      u16x4 pv;
#pragma unroll
      for (int rr = 0; rr < 4; ++rr) {
        float pp = __builtin_amdgcn_exp2f(sv[ni][rr] * C);
        su_acc += pp;
        pv[rr] = f2bf_fast(pp);
      }
      *(u16x4*)(Pw + lc*136 + (ni<<4) + (quad<<2)) = pv;
    }

    asm volatile("s_waitcnt vmcnt(0)" ::: "memory");
    __builtin_amdgcn_s_barrier();
  }

  // ---- final PV(31) ----
  {
    unsigned short* Pp = Ps[1] + w*2176;
#pragma unroll
    for (int kn = 0; kn < 4; ++kn) {
      short8 bp = *(const short8*)(Pp + lc*136 + (kn<<5) + (quad<<3));
#pragma unroll
      for (int dt = 0; dt < 4; ++dt)
        oacc[dt] = __builtin_amdgcn_mfma_f32_16x16x32_bf16(vfrag[kn][dt], bp, oacc[dt], 0, 0, 0);
    }
  }
#undef STAGE_KV

  // deferred cross-lane softmax-denominator reduction
  su_acc += __shfl_xor(su_acc, 16, 64);
  su_acc += __shfl_xor(su_acc, 32, 64);
  float invl = 1.0f / su_acc;
  int m = m0 + (w<<4) + lc;
#pragma unroll
  for (int dt = 0; dt < 4; ++dt) {
    int d = (dt<<4) + (quad<<2);
    size_t off = (((size_t)(b << 10) + m) << 10) + (h << 6) + d;
    f32x4 qv = *(const f32x4*)(Qf + off);
    f32x4 ov;
#pragma unroll
    for (int rr = 0; rr < 4; ++rr) ov[rr] = oacc[dt][rr]*invl + qv[rr];
    *(f32x4*)(out + off) = ov;
  }
}

extern "C" void kernel_launch(void* const* d_in, const int* in_sizes, int n_in,
                              void* d_out, int out_size, void* d_ws, size_t ws_size,
                              hipStream_t stream) {
  const float* x  = (const float*)d_in[0];
  const float* lw = (const float*)d_in[1];
  const float* lb = (const float*)d_in[2];
  const float* Wk = (const float*)d_in[3];
  const float* Wv = (const float*)d_in[4];
  const float* Wq = (const float*)d_in[5];
  float* out = (float*)d_out;

  char* ws = (char*)d_ws;
  size_t off = 0;
  unsigned short* xpad = (unsigned short*)(ws + off); off += (size_t)2*4102*1024*2;
  unsigned short* Wt   = (unsigned short*)(ws + off); off += (size_t)3072*7168*2;
  unsigned short* Ksg  = (unsigned short*)(ws + off); off += (size_t)32*2*4096*32*2;
  unsigned short* Vsg  = (unsigned short*)(ws + off); off += (size_t)32*128*64*32*2;
  unsigned short* Qsg  = (unsigned short*)(ws + off); off += (size_t)32*2*1024*32*2;
  float*          Qf   = (float*)(ws + off);          off += (size_t)2048*1024*4;
  float*          Qp   = (float*)(ws + off);          off += (size_t)8*2048*1024*4;

  for (int b = 0; b < 2; ++b) {
    hipMemsetAsync(xpad + (size_t)b*4102*1024, 0, 3*1024*2, stream);
    hipMemsetAsync(xpad + ((size_t)b*4102 + 4099)*1024, 0, 3*1024*2, stream);
  }
  ln_kernel<<<dim3(8192), dim3(256), 0, stream>>>(x, lw, lb, xpad);
  repack_kernel<<<dim3(1024, 3), dim3(256), 0, stream>>>(Wk, Wv, Wq, Wt);
  conv256<<<dim3(256), dim3(512), 0, stream>>>(xpad, Wt, Ksg, Vsg, Qp);
  qfinal<<<dim3(2048), dim3(256), 0, stream>>>(Qp, Qf, Qsg);
  attn_kernel<<<dim3(256), dim3(512), 0, stream>>>(Ksg, Vsg, Qsg, Qf, out);
}